// Round 6
// baseline (864.366 us; speedup 1.0000x reference)
//
#include <hip/hip_runtime.h>

#define C 128            // hidden/out channels
#define INCH 64          // input channels

__device__ __forceinline__ float silu_f(float v) {
    return v / (1.0f + __expf(-v));
}

struct __align__(8) DegCnt { float deg; int cnt; };

// ---------- preprocessing ----------

// deg=1 (self loop weight), cnt=0, cursor=0
__global__ void init_k(DegCnt* dc, int* cursor, int n) {
    int i = blockIdx.x * blockDim.x + threadIdx.x;
    if (i < n) { dc[i].deg = 1.0f; dc[i].cnt = 0; cursor[i] = 0; }
}

// two atomics per edge, but to the SAME 8-byte pair (one cacheline RMW)
__global__ void hist_k(const int* __restrict__ dst, const float* __restrict__ w,
                       DegCnt* dc, int E) {
    int e = blockIdx.x * blockDim.x + threadIdx.x;
    if (e < E) {
        int d = dst[e];
        atomicAdd(&dc[d].deg, w[e]);
        atomicAdd(&dc[d].cnt, 1);
    }
}

__global__ void extract_k(const DegCnt* __restrict__ dc,
                          int* counts, float* dinv, int n) {
    int i = blockIdx.x * blockDim.x + threadIdx.x;
    if (i < n) {
        counts[i] = dc[i].cnt;
        dinv[i] = rsqrtf(dc[i].deg);   // deg >= 1 (self-loop) so always > 0
    }
}

// ---------- exclusive scan of counts -> rowptr (1024 elems / block) ----------

#define SCAN_T 256
#define SCAN_E 1024

__global__ void scan1_k(const int* __restrict__ counts, int* rowptr, int* bsums, int N) {
    __shared__ int s[SCAN_T];
    int t = threadIdx.x;
    int base = blockIdx.x * SCAN_E + t * 4;
    int v[4];
    #pragma unroll
    for (int j = 0; j < 4; ++j) { int i = base + j; v[j] = (i < N) ? counts[i] : 0; }
    int sum = v[0] + v[1] + v[2] + v[3];
    s[t] = sum; __syncthreads();
    for (int off = 1; off < SCAN_T; off <<= 1) {
        int y = (t >= off) ? s[t - off] : 0;
        __syncthreads();
        s[t] += y;
        __syncthreads();
    }
    int incl = s[t];
    int excl = incl - sum;
    if (t == SCAN_T - 1) bsums[blockIdx.x] = incl;
    int run = excl;
    #pragma unroll
    for (int j = 0; j < 4; ++j) { int i = base + j; if (i < N) rowptr[i] = run; run += v[j]; }
}

__global__ void scan2_k(int* bsums, int nb) {
    __shared__ int s[128];
    int t = threadIdx.x;
    int v = (t < nb) ? bsums[t] : 0;
    s[t] = v; __syncthreads();
    for (int off = 1; off < 128; off <<= 1) {
        int y = (t >= off) ? s[t - off] : 0;
        __syncthreads();
        s[t] += y;
        __syncthreads();
    }
    if (t < nb) bsums[t] = s[t] - v;   // exclusive block offsets
}

__global__ void scan3_k(int* rowptr, const int* __restrict__ bsums, int N, int E) {
    int i = blockIdx.x * blockDim.x + threadIdx.x;
    if (i < N) rowptr[i] += bsums[i >> 10];
    if (i == 0) rowptr[N] = E;
}

// ---------- CSR fill: bucket edges by dst, fuse norm computation ----------

__global__ void fill_csr_k(const int* __restrict__ src, const int* __restrict__ dst,
                           const float* __restrict__ w, const float* __restrict__ dinv,
                           const int* __restrict__ rowptr, int* cursor,
                           int* esrc, float* enorm, int E) {
    int e = blockIdx.x * blockDim.x + threadIdx.x;
    if (e >= E) return;
    int s = src[e], d = dst[e];
    float nm = dinv[s] * w[e] * dinv[d];
    int pos = rowptr[d] + atomicAdd(&cursor[d], 1);
    esrc[pos] = s;
    enorm[pos] = nm;
}

// ---------- GEMM: H = act(x) @ W ----------
// act(x) = ACT ? silu(x + bias) : x   (bias = previous layer's bias)

template<int K, bool ACT>
__launch_bounds__(256, 2)
__global__ void gemm_k(const float* __restrict__ x, const float* __restrict__ W,
                       const float* __restrict__ bias, float* __restrict__ H, int N) {
    __shared__ float Ws[K][C];
    __shared__ float Xs[32][K];
    const int tid = threadIdx.x;
    const int r0 = blockIdx.x * 32;

    for (int i4 = tid; i4 < (K * C) / 4; i4 += 256) {
        *(float4*)&Ws[(i4 * 4) / C][(i4 * 4) % C] = *(const float4*)&W[i4 * 4];
    }
    for (int i4 = tid; i4 < (32 * K) / 4; i4 += 256) {
        int base = i4 * 4;
        int r = base / K, k = base % K;
        float4 v = make_float4(0.f, 0.f, 0.f, 0.f);
        if (r0 + r < N) {
            v = *(const float4*)&x[(size_t)(r0 + r) * K + k];
            if (ACT) {
                v.x = silu_f(v.x + bias[k + 0]);
                v.y = silu_f(v.y + bias[k + 1]);
                v.z = silu_f(v.z + bias[k + 2]);
                v.w = silu_f(v.w + bias[k + 3]);
            }
        }
        *(float4*)&Xs[r][k] = v;
    }
    __syncthreads();

    const int cg = (tid & 31) * 4;   // col base (0..124)
    const int rg = (tid >> 5) * 4;   // row base (0..28)
    float acc[4][4] = {};
    for (int k = 0; k < K; ++k) {
        float4 wv = *(const float4*)&Ws[k][cg];
        float xr0 = Xs[rg + 0][k];
        float xr1 = Xs[rg + 1][k];
        float xr2 = Xs[rg + 2][k];
        float xr3 = Xs[rg + 3][k];
        acc[0][0] = fmaf(xr0, wv.x, acc[0][0]); acc[0][1] = fmaf(xr0, wv.y, acc[0][1]);
        acc[0][2] = fmaf(xr0, wv.z, acc[0][2]); acc[0][3] = fmaf(xr0, wv.w, acc[0][3]);
        acc[1][0] = fmaf(xr1, wv.x, acc[1][0]); acc[1][1] = fmaf(xr1, wv.y, acc[1][1]);
        acc[1][2] = fmaf(xr1, wv.z, acc[1][2]); acc[1][3] = fmaf(xr1, wv.w, acc[1][3]);
        acc[2][0] = fmaf(xr2, wv.x, acc[2][0]); acc[2][1] = fmaf(xr2, wv.y, acc[2][1]);
        acc[2][2] = fmaf(xr2, wv.z, acc[2][2]); acc[2][3] = fmaf(xr2, wv.w, acc[2][3]);
        acc[3][0] = fmaf(xr3, wv.x, acc[3][0]); acc[3][1] = fmaf(xr3, wv.y, acc[3][1]);
        acc[3][2] = fmaf(xr3, wv.z, acc[3][2]); acc[3][3] = fmaf(xr3, wv.w, acc[3][3]);
    }

    #pragma unroll
    for (int i = 0; i < 4; ++i) {
        int r = r0 + rg + i;
        if (r < N) {
            *(float4*)&H[(size_t)r * C + cg] =
                make_float4(acc[i][0], acc[i][1], acc[i][2], acc[i][3]);
        }
    }
}

// ---------- aggregation (gather): acc[d] = H[d]*dinv[d]^2 + sum_e H[src_e]*norm_e ----------
// one 64-lane wave per dst node; lane owns 2 channels (float2).
// Edge metadata loaded cooperatively (64 edges / coalesced 256B) and shfl-broadcast.
// POOL=false: write acc -> AGG[d].
// POOL=true : silu(acc + bias) then block-reduce 4 waves -> partial[block][128] (layer 3).

template<bool POOL>
__launch_bounds__(256)
__global__ void agg_gather_k(const float* __restrict__ H, const int* __restrict__ esrc,
                             const float* __restrict__ enorm, const int* __restrict__ rowptr,
                             const float* __restrict__ dinv, const float* __restrict__ bias,
                             float* __restrict__ outbuf, int N) {
    const int wid  = threadIdx.x >> 6;
    const int lane = threadIdx.x & 63;
    const int d = blockIdx.x * 4 + wid;
    const bool active = d < N;
    const int c = lane * 2;

    float2 a0 = make_float2(0.f, 0.f);
    float2 a1 = make_float2(0.f, 0.f);
    int beg = 0, end = 0;
    if (active) {
        float di = dinv[d];
        float d2 = di * di;
        float2 h = *(const float2*)&H[(size_t)d * C + c];
        a0.x = h.x * d2; a0.y = h.y * d2;
        beg = rowptr[d]; end = rowptr[d + 1];
    }
    while (beg < end) {                       // wave-uniform bounds
        int cnt = end - beg; if (cnt > 64) cnt = 64;
        int es = 0; float nm = 0.f;
        if (lane < cnt) { es = esrc[beg + lane]; nm = enorm[beg + lane]; }
        int j = 0;
        for (; j + 1 < cnt; j += 2) {
            int   s0 = __shfl(es, j);     float n0 = __shfl(nm, j);
            int   s1 = __shfl(es, j + 1); float n1 = __shfl(nm, j + 1);
            float2 v0 = *(const float2*)&H[(size_t)s0 * C + c];
            float2 v1 = *(const float2*)&H[(size_t)s1 * C + c];
            a0.x = fmaf(v0.x, n0, a0.x); a0.y = fmaf(v0.y, n0, a0.y);
            a1.x = fmaf(v1.x, n1, a1.x); a1.y = fmaf(v1.y, n1, a1.y);
        }
        if (j < cnt) {
            int s0 = __shfl(es, j); float n0 = __shfl(nm, j);
            float2 v0 = *(const float2*)&H[(size_t)s0 * C + c];
            a0.x = fmaf(v0.x, n0, a0.x); a0.y = fmaf(v0.y, n0, a0.y);
        }
        beg += cnt;
    }
    float2 acc = make_float2(a0.x + a1.x, a0.y + a1.y);

    if (!POOL) {
        if (active) *(float2*)&outbuf[(size_t)d * C + c] = acc;
    } else {
        __shared__ float2 red[4][64];
        float2 v = make_float2(0.f, 0.f);
        if (active) {
            v.x = silu_f(acc.x + bias[c]);
            v.y = silu_f(acc.y + bias[c + 1]);
        }
        red[wid][lane] = v;
        __syncthreads();
        if (threadIdx.x < 64) {
            float2 t0 = red[0][lane], t1 = red[1][lane];
            float2 t2 = red[2][lane], t3 = red[3][lane];
            float2 t = make_float2(t0.x + t1.x + t2.x + t3.x,
                                   t0.y + t1.y + t2.y + t3.y);
            *(float2*)&outbuf[(size_t)blockIdx.x * C + c] = t;
        }
    }
}

// ---------- 2-stage reduce of partials -> out ----------

__global__ void reduce1_k(const float* __restrict__ partial, float* __restrict__ p2,
                          int NB, int chunk) {
    int t = threadIdx.x;                      // 128 = channel
    int r0 = blockIdx.x * chunk;
    int r1 = r0 + chunk; if (r1 > NB) r1 = NB;
    float s = 0.f;
    for (int r = r0; r < r1; ++r) s += partial[(size_t)r * C + t];
    p2[(size_t)blockIdx.x * C + t] = s;
}

__global__ void reduce2_k(const float* __restrict__ p2, float* __restrict__ out,
                          int R1, float inv_n) {
    int t = threadIdx.x;                      // 128 = channel
    float s = 0.f;
    for (int r = 0; r < R1; ++r) s += p2[(size_t)r * C + t];
    out[t] = s * inv_n;
}

// ---------- launch ----------

extern "C" void kernel_launch(void* const* d_in, const int* in_sizes, int n_in,
                              void* d_out, int out_size, void* d_ws, size_t ws_size,
                              hipStream_t stream) {
    const float* x  = (const float*)d_in[0];
    const int*   ei = (const int*)d_in[1];
    const float* ew = (const float*)d_in[2];
    const float* W1 = (const float*)d_in[3];
    const float* b1 = (const float*)d_in[4];
    const float* W2 = (const float*)d_in[5];
    const float* b2 = (const float*)d_in[6];
    const float* W3 = (const float*)d_in[7];
    const float* b3 = (const float*)d_in[8];
    float* out = (float*)d_out;

    const int N = in_sizes[0] / INCH;
    const int E = in_sizes[1] / 2;
    const int* src = ei;
    const int* dst = ei + E;

    char* ws = (char*)d_ws;
    size_t off = 0;
    auto alloc = [&](size_t bytes) -> void* {
        void* p = ws + off;
        off += (bytes + 255) & ~(size_t)255;
        return p;
    };
    float*  H      = (float*) alloc((size_t)N * C * sizeof(float));
    float*  AGG    = (float*) alloc((size_t)N * C * sizeof(float));
    int*    esrc   = (int*)   alloc((size_t)E * sizeof(int));
    float*  enorm  = (float*) alloc((size_t)E * sizeof(float));
    int*    rowptr = (int*)   alloc((size_t)(N + 1) * sizeof(int));
    DegCnt* dc     = (DegCnt*)alloc((size_t)N * sizeof(DegCnt));
    int*    counts = (int*)   alloc((size_t)N * sizeof(int));
    int*    cursor = (int*)   alloc((size_t)N * sizeof(int));
    float*  dinv   = (float*) alloc((size_t)N * sizeof(float));
    int*    bsums  = (int*)   alloc(256 * sizeof(int));
    (void)ws_size;

    const int nb = (N + 255) / 256;
    const int eb = (E + 255) / 256;
    const int sbk = (N + SCAN_E - 1) / SCAN_E;   // scan blocks (<=128)

    // normalization + CSR build
    init_k<<<nb, 256, 0, stream>>>(dc, cursor, N);
    hist_k<<<eb, 256, 0, stream>>>(dst, ew, dc, E);
    extract_k<<<nb, 256, 0, stream>>>(dc, counts, dinv, N);
    scan1_k<<<sbk, SCAN_T, 0, stream>>>(counts, rowptr, bsums, N);
    scan2_k<<<1, 128, 0, stream>>>(bsums, sbk);
    scan3_k<<<nb, 256, 0, stream>>>(rowptr, bsums, N, E);
    fill_csr_k<<<eb, 256, 0, stream>>>(src, dst, ew, dinv, rowptr, cursor, esrc, enorm, E);

    const int gb  = (N + 31) / 32;             // gemm blocks
    const int ab  = (N + 3) / 4;               // agg blocks (4 waves/block)

    // layer 1: x(64) -> H, aggregate -> AGG
    gemm_k<INCH, false><<<gb, 256, 0, stream>>>(x, W1, nullptr, H, N);
    agg_gather_k<false><<<ab, 256, 0, stream>>>(H, esrc, enorm, rowptr, dinv, nullptr, AGG, N);
    // layer 2: silu(AGG+b1)(128) -> H, aggregate
    gemm_k<C, true><<<gb, 256, 0, stream>>>(AGG, W2, b1, H, N);
    agg_gather_k<false><<<ab, 256, 0, stream>>>(H, esrc, enorm, rowptr, dinv, nullptr, AGG, N);
    // layer 3: gemm -> H, fused aggregate + bias + silu + block-pool -> partials (alias AGG)
    gemm_k<C, true><<<gb, 256, 0, stream>>>(AGG, W3, b2, H, N);
    float* partial = AGG;                      // AGG free in POOL mode
    agg_gather_k<true><<<ab, 256, 0, stream>>>(H, esrc, enorm, rowptr, dinv, b3, partial, N);

    // 2-stage mean reduce: partial[ab][128] -> p2[R1][128] -> out[128]
    const int R1 = 100;
    const int chunk = (ab + R1 - 1) / R1;
    float* p2 = (float*)counts;                // counts free after scan
    reduce1_k<<<R1, 128, 0, stream>>>(partial, p2, ab, chunk);
    reduce2_k<<<1, 128, 0, stream>>>(p2, out, R1, 1.0f / (float)N);
}

// Round 7
// 790.113 us; speedup vs baseline: 1.0940x; 1.0940x over previous
//
#include <hip/hip_runtime.h>

#define C 128            // hidden/out channels
#define INCH 64          // input channels
#define FIXP 33554432.0f // 2^25 fixed-point scale for weighted degree

__device__ __forceinline__ float silu_f(float v) {
    return v / (1.0f + __expf(-v));
}

// ---------- preprocessing ----------

__global__ void init_k(unsigned long long* packed, int* cursor, int n) {
    int i = blockIdx.x * blockDim.x + threadIdx.x;
    if (i < n) { packed[i] = 0ull; cursor[i] = 0; }
}

// one u64 atomic per edge: hi32 = count, lo32 = fixed-point sum of w
__global__ void hist_k(const int* __restrict__ dst, const float* __restrict__ w,
                       unsigned long long* packed, int E) {
    int e = blockIdx.x * blockDim.x + threadIdx.x;
    if (e < E) {
        unsigned fx = (unsigned)(w[e] * FIXP + 0.5f);
        atomicAdd(&packed[dst[e]], (1ull << 32) | (unsigned long long)fx);
    }
}

__global__ void extract_k(const unsigned long long* __restrict__ packed,
                          int* counts, float* dinv, int n) {
    int i = blockIdx.x * blockDim.x + threadIdx.x;
    if (i < n) {
        unsigned long long p = packed[i];
        counts[i] = (int)(p >> 32);
        float deg = 1.0f + (float)(unsigned)(p & 0xffffffffull) * (1.0f / FIXP);
        dinv[i] = rsqrtf(deg);   // deg >= 1 (self-loop) so always > 0
    }
}

// ---------- exclusive scan of counts -> rowptr (1024 elems / block) ----------

#define SCAN_T 256
#define SCAN_E 1024

__global__ void scan1_k(const int* __restrict__ counts, int* rowptr, int* bsums, int N) {
    __shared__ int s[SCAN_T];
    int t = threadIdx.x;
    int base = blockIdx.x * SCAN_E + t * 4;
    int v[4];
    #pragma unroll
    for (int j = 0; j < 4; ++j) { int i = base + j; v[j] = (i < N) ? counts[i] : 0; }
    int sum = v[0] + v[1] + v[2] + v[3];
    s[t] = sum; __syncthreads();
    for (int off = 1; off < SCAN_T; off <<= 1) {
        int y = (t >= off) ? s[t - off] : 0;
        __syncthreads();
        s[t] += y;
        __syncthreads();
    }
    int incl = s[t];
    int excl = incl - sum;
    if (t == SCAN_T - 1) bsums[blockIdx.x] = incl;
    int run = excl;
    #pragma unroll
    for (int j = 0; j < 4; ++j) { int i = base + j; if (i < N) rowptr[i] = run; run += v[j]; }
}

__global__ void scan2_k(int* bsums, int nb) {
    __shared__ int s[128];
    int t = threadIdx.x;
    int v = (t < nb) ? bsums[t] : 0;
    s[t] = v; __syncthreads();
    for (int off = 1; off < 128; off <<= 1) {
        int y = (t >= off) ? s[t - off] : 0;
        __syncthreads();
        s[t] += y;
        __syncthreads();
    }
    if (t < nb) bsums[t] = s[t] - v;   // exclusive block offsets
}

__global__ void scan3_k(int* rowptr, const int* __restrict__ bsums, int N, int E) {
    int i = blockIdx.x * blockDim.x + threadIdx.x;
    if (i < N) rowptr[i] += bsums[i >> 10];
    if (i == 0) rowptr[N] = E;
}

// ---------- CSR fill: bucket edges by dst, fuse norm computation ----------

__global__ void fill_csr_k(const int* __restrict__ src, const int* __restrict__ dst,
                           const float* __restrict__ w, const float* __restrict__ dinv,
                           const int* __restrict__ rowptr, int* cursor,
                           int* esrc, float* enorm, int E) {
    int e = blockIdx.x * blockDim.x + threadIdx.x;
    if (e >= E) return;
    int s = src[e], d = dst[e];
    float nm = dinv[s] * w[e] * dinv[d];
    int pos = rowptr[d] + atomicAdd(&cursor[d], 1);
    esrc[pos] = s;
    enorm[pos] = nm;
}

// ---------- GEMM: H = act(x) @ W ----------
// act(x) = ACT ? silu(x + bias) : x   (bias = previous layer's bias)

template<int K, bool ACT>
__launch_bounds__(256, 2)
__global__ void gemm_k(const float* __restrict__ x, const float* __restrict__ W,
                       const float* __restrict__ bias, float* __restrict__ H, int N) {
    __shared__ float Ws[K][C];
    __shared__ float Xs[32][K];
    const int tid = threadIdx.x;
    const int r0 = blockIdx.x * 32;

    for (int i4 = tid; i4 < (K * C) / 4; i4 += 256) {
        *(float4*)&Ws[(i4 * 4) / C][(i4 * 4) % C] = *(const float4*)&W[i4 * 4];
    }
    for (int i4 = tid; i4 < (32 * K) / 4; i4 += 256) {
        int base = i4 * 4;
        int r = base / K, k = base % K;
        float4 v = make_float4(0.f, 0.f, 0.f, 0.f);
        if (r0 + r < N) {
            v = *(const float4*)&x[(size_t)(r0 + r) * K + k];
            if (ACT) {
                v.x = silu_f(v.x + bias[k + 0]);
                v.y = silu_f(v.y + bias[k + 1]);
                v.z = silu_f(v.z + bias[k + 2]);
                v.w = silu_f(v.w + bias[k + 3]);
            }
        }
        *(float4*)&Xs[r][k] = v;
    }
    __syncthreads();

    const int cg = (tid & 31) * 4;   // col base (0..124)
    const int rg = (tid >> 5) * 4;   // row base (0..28)
    float acc[4][4] = {};
    for (int k = 0; k < K; ++k) {
        float4 wv = *(const float4*)&Ws[k][cg];
        float xr0 = Xs[rg + 0][k];
        float xr1 = Xs[rg + 1][k];
        float xr2 = Xs[rg + 2][k];
        float xr3 = Xs[rg + 3][k];
        acc[0][0] = fmaf(xr0, wv.x, acc[0][0]); acc[0][1] = fmaf(xr0, wv.y, acc[0][1]);
        acc[0][2] = fmaf(xr0, wv.z, acc[0][2]); acc[0][3] = fmaf(xr0, wv.w, acc[0][3]);
        acc[1][0] = fmaf(xr1, wv.x, acc[1][0]); acc[1][1] = fmaf(xr1, wv.y, acc[1][1]);
        acc[1][2] = fmaf(xr1, wv.z, acc[1][2]); acc[1][3] = fmaf(xr1, wv.w, acc[1][3]);
        acc[2][0] = fmaf(xr2, wv.x, acc[2][0]); acc[2][1] = fmaf(xr2, wv.y, acc[2][1]);
        acc[2][2] = fmaf(xr2, wv.z, acc[2][2]); acc[2][3] = fmaf(xr2, wv.w, acc[2][3]);
        acc[3][0] = fmaf(xr3, wv.x, acc[3][0]); acc[3][1] = fmaf(xr3, wv.y, acc[3][1]);
        acc[3][2] = fmaf(xr3, wv.z, acc[3][2]); acc[3][3] = fmaf(xr3, wv.w, acc[3][3]);
    }

    #pragma unroll
    for (int i = 0; i < 4; ++i) {
        int r = r0 + rg + i;
        if (r < N) {
            *(float4*)&H[(size_t)r * C + cg] =
                make_float4(acc[i][0], acc[i][1], acc[i][2], acc[i][3]);
        }
    }
}

// ---------- aggregation (gather): acc[d] = H[d]*dinv[d]^2 + sum_e H[src_e]*norm_e ----------
// one 64-lane wave per dst node; lane owns 2 channels (float2).
// POOL=false: write acc -> AGG[d].
// POOL=true : silu(acc + bias) then block-reduce 4 waves -> partial[block][128] (layer 3).

template<bool POOL>
__launch_bounds__(256)
__global__ void agg_gather_k(const float* __restrict__ H, const int* __restrict__ esrc,
                             const float* __restrict__ enorm, const int* __restrict__ rowptr,
                             const float* __restrict__ dinv, const float* __restrict__ bias,
                             float* __restrict__ outbuf, int N) {
    const int wid  = threadIdx.x >> 6;
    const int lane = threadIdx.x & 63;
    const int d = blockIdx.x * 4 + wid;
    const bool active = d < N;
    const int c = lane * 2;

    float2 a0 = make_float2(0.f, 0.f);
    float2 a1 = make_float2(0.f, 0.f);
    int beg = 0, end = 0;
    if (active) {
        float di = dinv[d];
        float d2 = di * di;
        float2 h = *(const float2*)&H[(size_t)d * C + c];
        a0.x = h.x * d2; a0.y = h.y * d2;
        beg = rowptr[d]; end = rowptr[d + 1];
    }
    while (beg < end) {                       // wave-uniform bounds
        int cnt = end - beg; if (cnt > 64) cnt = 64;
        int es = 0; float nm = 0.f;
        if (lane < cnt) { es = esrc[beg + lane]; nm = enorm[beg + lane]; }
        int j = 0;
        for (; j + 1 < cnt; j += 2) {
            int   s0 = __shfl(es, j);     float n0 = __shfl(nm, j);
            int   s1 = __shfl(es, j + 1); float n1 = __shfl(nm, j + 1);
            float2 v0 = *(const float2*)&H[(size_t)s0 * C + c];
            float2 v1 = *(const float2*)&H[(size_t)s1 * C + c];
            a0.x = fmaf(v0.x, n0, a0.x); a0.y = fmaf(v0.y, n0, a0.y);
            a1.x = fmaf(v1.x, n1, a1.x); a1.y = fmaf(v1.y, n1, a1.y);
        }
        if (j < cnt) {
            int s0 = __shfl(es, j); float n0 = __shfl(nm, j);
            float2 v0 = *(const float2*)&H[(size_t)s0 * C + c];
            a0.x = fmaf(v0.x, n0, a0.x); a0.y = fmaf(v0.y, n0, a0.y);
        }
        beg += cnt;
    }
    float2 acc = make_float2(a0.x + a1.x, a0.y + a1.y);

    if (!POOL) {
        if (active) *(float2*)&outbuf[(size_t)d * C + c] = acc;
    } else {
        __shared__ float2 red[4][64];
        float2 v = make_float2(0.f, 0.f);
        if (active) {
            v.x = silu_f(acc.x + bias[c]);
            v.y = silu_f(acc.y + bias[c + 1]);
        }
        red[wid][lane] = v;
        __syncthreads();
        if (threadIdx.x < 64) {
            float2 t0 = red[0][lane], t1 = red[1][lane];
            float2 t2 = red[2][lane], t3 = red[3][lane];
            float2 t = make_float2(t0.x + t1.x + t2.x + t3.x,
                                   t0.y + t1.y + t2.y + t3.y);
            *(float2*)&outbuf[(size_t)blockIdx.x * C + c] = t;
        }
    }
}

// ---------- 2-stage reduce of partials -> out ----------

__global__ void reduce1_k(const float* __restrict__ partial, float* __restrict__ p2,
                          int NB, int chunk) {
    int t = threadIdx.x;                      // 128 = channel
    int r0 = blockIdx.x * chunk;
    int r1 = r0 + chunk; if (r1 > NB) r1 = NB;
    float s = 0.f;
    for (int r = r0; r < r1; ++r) s += partial[(size_t)r * C + t];
    p2[(size_t)blockIdx.x * C + t] = s;
}

__global__ void reduce2_k(const float* __restrict__ p2, float* __restrict__ out,
                          int R1, float inv_n) {
    int t = threadIdx.x;                      // 128 = channel
    float s = 0.f;
    for (int r = 0; r < R1; ++r) s += p2[(size_t)r * C + t];
    out[t] = s * inv_n;
}

// ---------- launch ----------

extern "C" void kernel_launch(void* const* d_in, const int* in_sizes, int n_in,
                              void* d_out, int out_size, void* d_ws, size_t ws_size,
                              hipStream_t stream) {
    const float* x  = (const float*)d_in[0];
    const int*   ei = (const int*)d_in[1];
    const float* ew = (const float*)d_in[2];
    const float* W1 = (const float*)d_in[3];
    const float* b1 = (const float*)d_in[4];
    const float* W2 = (const float*)d_in[5];
    const float* b2 = (const float*)d_in[6];
    const float* W3 = (const float*)d_in[7];
    const float* b3 = (const float*)d_in[8];
    float* out = (float*)d_out;

    const int N = in_sizes[0] / INCH;
    const int E = in_sizes[1] / 2;
    const int* src = ei;
    const int* dst = ei + E;

    char* ws = (char*)d_ws;
    size_t off = 0;
    auto alloc = [&](size_t bytes) -> void* {
        void* p = ws + off;
        off += (bytes + 255) & ~(size_t)255;
        return p;
    };
    float*  H      = (float*) alloc((size_t)N * C * sizeof(float));
    float*  AGG    = (float*) alloc((size_t)N * C * sizeof(float));
    int*    esrc   = (int*)   alloc((size_t)E * sizeof(int));
    float*  enorm  = (float*) alloc((size_t)E * sizeof(float));
    int*    rowptr = (int*)   alloc((size_t)(N + 1) * sizeof(int));
    unsigned long long* packed = (unsigned long long*)alloc((size_t)N * 8);
    int*    counts = (int*)   alloc((size_t)N * sizeof(int));
    int*    cursor = (int*)   alloc((size_t)N * sizeof(int));
    float*  dinv   = (float*) alloc((size_t)N * sizeof(float));
    int*    bsums  = (int*)   alloc(256 * sizeof(int));
    (void)ws_size;

    const int nb = (N + 255) / 256;
    const int eb = (E + 255) / 256;
    const int sbk = (N + SCAN_E - 1) / SCAN_E;   // scan blocks (<=128)

    // normalization + CSR build
    init_k<<<nb, 256, 0, stream>>>(packed, cursor, N);
    hist_k<<<eb, 256, 0, stream>>>(dst, ew, packed, E);
    extract_k<<<nb, 256, 0, stream>>>(packed, counts, dinv, N);
    scan1_k<<<sbk, SCAN_T, 0, stream>>>(counts, rowptr, bsums, N);
    scan2_k<<<1, 128, 0, stream>>>(bsums, sbk);
    scan3_k<<<nb, 256, 0, stream>>>(rowptr, bsums, N, E);
    fill_csr_k<<<eb, 256, 0, stream>>>(src, dst, ew, dinv, rowptr, cursor, esrc, enorm, E);

    const int gb  = (N + 31) / 32;             // gemm blocks
    const int ab  = (N + 3) / 4;               // agg blocks (4 waves/block)

    // layer 1: x(64) -> H, aggregate -> AGG
    gemm_k<INCH, false><<<gb, 256, 0, stream>>>(x, W1, nullptr, H, N);
    agg_gather_k<false><<<ab, 256, 0, stream>>>(H, esrc, enorm, rowptr, dinv, nullptr, AGG, N);
    // layer 2: silu(AGG+b1)(128) -> H, aggregate
    gemm_k<C, true><<<gb, 256, 0, stream>>>(AGG, W2, b1, H, N);
    agg_gather_k<false><<<ab, 256, 0, stream>>>(H, esrc, enorm, rowptr, dinv, nullptr, AGG, N);
    // layer 3: gemm -> H, fused aggregate + bias + silu + block-pool -> partials (alias AGG)
    gemm_k<C, true><<<gb, 256, 0, stream>>>(AGG, W3, b2, H, N);
    float* partial = AGG;                      // AGG free in POOL mode
    agg_gather_k<true><<<ab, 256, 0, stream>>>(H, esrc, enorm, rowptr, dinv, b3, partial, N);

    // 2-stage mean reduce: partial[ab][128] -> p2[R1][128] -> out[128]
    const int R1 = 100;
    const int chunk = (ab + R1 - 1) / R1;
    float* p2 = (float*)counts;                // counts free after scan
    reduce1_k<<<R1, 128, 0, stream>>>(partial, p2, ab, chunk);
    reduce2_k<<<1, 128, 0, stream>>>(p2, out, R1, 1.0f / (float)N);
}

// Round 8
// 738.491 us; speedup vs baseline: 1.1704x; 1.0699x over previous
//
#include <hip/hip_runtime.h>

#define C 128            // hidden/out channels
#define INCH 64          // input channels
#define FIXP 33554432.0f // 2^25 fixed-point scale for weighted degree

__device__ __forceinline__ float silu_f(float v) {
    return v / (1.0f + __expf(-v));
}

// ---------- preprocessing ----------

__global__ void init_k(unsigned long long* packed, int* cursor, int n) {
    int i = blockIdx.x * blockDim.x + threadIdx.x;
    if (i < n) { packed[i] = 0ull; cursor[i] = 0; }
}

// one u64 atomic per edge: hi32 = count, lo32 = fixed-point sum of w
__global__ void hist_k(const int* __restrict__ dst, const float* __restrict__ w,
                       unsigned long long* packed, int E) {
    int e = blockIdx.x * blockDim.x + threadIdx.x;
    if (e < E) {
        unsigned fx = (unsigned)(w[e] * FIXP + 0.5f);
        atomicAdd(&packed[dst[e]], (1ull << 32) | (unsigned long long)fx);
    }
}

__global__ void extract_k(const unsigned long long* __restrict__ packed,
                          int* counts, float* dinv, int n) {
    int i = blockIdx.x * blockDim.x + threadIdx.x;
    if (i < n) {
        unsigned long long p = packed[i];
        counts[i] = (int)(p >> 32);
        float deg = 1.0f + (float)(unsigned)(p & 0xffffffffull) * (1.0f / FIXP);
        dinv[i] = rsqrtf(deg);   // deg >= 1 (self-loop) so always > 0
    }
}

// ---------- exclusive scan of counts -> rowptr (1024 elems / block) ----------

#define SCAN_T 256
#define SCAN_E 1024

__global__ void scan1_k(const int* __restrict__ counts, int* rowptr, int* bsums, int N) {
    __shared__ int s[SCAN_T];
    int t = threadIdx.x;
    int base = blockIdx.x * SCAN_E + t * 4;
    int v[4];
    #pragma unroll
    for (int j = 0; j < 4; ++j) { int i = base + j; v[j] = (i < N) ? counts[i] : 0; }
    int sum = v[0] + v[1] + v[2] + v[3];
    s[t] = sum; __syncthreads();
    for (int off = 1; off < SCAN_T; off <<= 1) {
        int y = (t >= off) ? s[t - off] : 0;
        __syncthreads();
        s[t] += y;
        __syncthreads();
    }
    int incl = s[t];
    int excl = incl - sum;
    if (t == SCAN_T - 1) bsums[blockIdx.x] = incl;
    int run = excl;
    #pragma unroll
    for (int j = 0; j < 4; ++j) { int i = base + j; if (i < N) rowptr[i] = run; run += v[j]; }
}

__global__ void scan2_k(int* bsums, int nb) {
    __shared__ int s[128];
    int t = threadIdx.x;
    int v = (t < nb) ? bsums[t] : 0;
    s[t] = v; __syncthreads();
    for (int off = 1; off < 128; off <<= 1) {
        int y = (t >= off) ? s[t - off] : 0;
        __syncthreads();
        s[t] += y;
        __syncthreads();
    }
    if (t < nb) bsums[t] = s[t] - v;   // exclusive block offsets
}

__global__ void scan3_k(int* rowptr, const int* __restrict__ bsums, int N, int E) {
    int i = blockIdx.x * blockDim.x + threadIdx.x;
    if (i < N) rowptr[i] += bsums[i >> 10];
    if (i == 0) rowptr[N] = E;
}

// ---------- CSR fill: edata[pos] = {src, norm} (single 8B store) ----------

__global__ void fill_csr_k(const int* __restrict__ src, const int* __restrict__ dst,
                           const float* __restrict__ w, const float* __restrict__ dinv,
                           const int* __restrict__ rowptr, int* cursor,
                           int2* edata, int E) {
    int e = blockIdx.x * blockDim.x + threadIdx.x;
    if (e >= E) return;
    int s = src[e], d = dst[e];
    float nm = dinv[s] * w[e] * dinv[d];
    int pos = rowptr[d] + atomicAdd(&cursor[d], 1);
    edata[pos] = make_int2(s, __float_as_int(nm));
}

// ---------- GEMM: H = act(x) @ W ----------
// act(x) = ACT ? silu(x + bias) : x   (bias = previous layer's bias)

template<int K, bool ACT>
__launch_bounds__(256, 2)
__global__ void gemm_k(const float* __restrict__ x, const float* __restrict__ W,
                       const float* __restrict__ bias, float* __restrict__ H, int N) {
    __shared__ float Ws[K][C];
    __shared__ float Xs[32][K];
    const int tid = threadIdx.x;
    const int r0 = blockIdx.x * 32;

    for (int i4 = tid; i4 < (K * C) / 4; i4 += 256) {
        *(float4*)&Ws[(i4 * 4) / C][(i4 * 4) % C] = *(const float4*)&W[i4 * 4];
    }
    for (int i4 = tid; i4 < (32 * K) / 4; i4 += 256) {
        int base = i4 * 4;
        int r = base / K, k = base % K;
        float4 v = make_float4(0.f, 0.f, 0.f, 0.f);
        if (r0 + r < N) {
            v = *(const float4*)&x[(size_t)(r0 + r) * K + k];
            if (ACT) {
                v.x = silu_f(v.x + bias[k + 0]);
                v.y = silu_f(v.y + bias[k + 1]);
                v.z = silu_f(v.z + bias[k + 2]);
                v.w = silu_f(v.w + bias[k + 3]);
            }
        }
        *(float4*)&Xs[r][k] = v;
    }
    __syncthreads();

    const int cg = (tid & 31) * 4;   // col base (0..124)
    const int rg = (tid >> 5) * 4;   // row base (0..28)
    float acc[4][4] = {};
    for (int k = 0; k < K; ++k) {
        float4 wv = *(const float4*)&Ws[k][cg];
        float xr0 = Xs[rg + 0][k];
        float xr1 = Xs[rg + 1][k];
        float xr2 = Xs[rg + 2][k];
        float xr3 = Xs[rg + 3][k];
        acc[0][0] = fmaf(xr0, wv.x, acc[0][0]); acc[0][1] = fmaf(xr0, wv.y, acc[0][1]);
        acc[0][2] = fmaf(xr0, wv.z, acc[0][2]); acc[0][3] = fmaf(xr0, wv.w, acc[0][3]);
        acc[1][0] = fmaf(xr1, wv.x, acc[1][0]); acc[1][1] = fmaf(xr1, wv.y, acc[1][1]);
        acc[1][2] = fmaf(xr1, wv.z, acc[1][2]); acc[1][3] = fmaf(xr1, wv.w, acc[1][3]);
        acc[2][0] = fmaf(xr2, wv.x, acc[2][0]); acc[2][1] = fmaf(xr2, wv.y, acc[2][1]);
        acc[2][2] = fmaf(xr2, wv.z, acc[2][2]); acc[2][3] = fmaf(xr2, wv.w, acc[2][3]);
        acc[3][0] = fmaf(xr3, wv.x, acc[3][0]); acc[3][1] = fmaf(xr3, wv.y, acc[3][1]);
        acc[3][2] = fmaf(xr3, wv.z, acc[3][2]); acc[3][3] = fmaf(xr3, wv.w, acc[3][3]);
    }

    #pragma unroll
    for (int i = 0; i < 4; ++i) {
        int r = r0 + rg + i;
        if (r < N) {
            *(float4*)&H[(size_t)r * C + cg] =
                make_float4(acc[i][0], acc[i][1], acc[i][2], acc[i][3]);
        }
    }
}

// ---------- aggregation (gather): acc[d] = H[d]*dinv[d]^2 + sum_e H[src_e]*norm_e ----------
// one 32-lane GROUP per dst node (8 nodes/block); lane owns float4 (4 ch).
// Edge metadata read directly per group (same addr for 32 lanes -> broadcast load).
// NO cross-lane ops in the edge path (round-4/5 bug was shfl in divergent loop).
// Edge loop 4-deep unrolled, clamp-and-zero predication -> branch-free, 4 rows in flight.
// POOL=false: write acc -> outbuf[d].
// POOL=true : silu(acc + bias) then block-reduce 8 groups -> partial[block][128].

template<bool POOL>
__launch_bounds__(256)
__global__ void agg_gather_k(const float* __restrict__ H, const int2* __restrict__ edata,
                             const int* __restrict__ rowptr, const float* __restrict__ dinv,
                             const float* __restrict__ bias, float* __restrict__ outbuf, int N) {
    const int g = threadIdx.x >> 5;      // group 0..7
    const int l = threadIdx.x & 31;      // lane in group
    const int d = blockIdx.x * 8 + g;
    const bool active = d < N;
    const int c = l * 4;                 // channel base 0..124

    float4 a0 = make_float4(0.f, 0.f, 0.f, 0.f);
    float4 a1 = a0, a2 = a0, a3 = a0;
    if (active) {
        float di = dinv[d];
        float d2 = di * di;
        float4 h = *(const float4*)&H[(size_t)d * C + c];
        a0 = make_float4(h.x * d2, h.y * d2, h.z * d2, h.w * d2);
        const int beg = rowptr[d], end = rowptr[d + 1];
        for (int j = beg; j < end; j += 4) {
            int j1 = j + 1, j2 = j + 2, j3 = j + 3;
            int2 m0 = edata[j];
            int2 m1 = edata[j1 < end ? j1 : j];
            int2 m2 = edata[j2 < end ? j2 : j];
            int2 m3 = edata[j3 < end ? j3 : j];
            float n0 = __int_as_float(m0.y);
            float n1 = j1 < end ? __int_as_float(m1.y) : 0.f;
            float n2 = j2 < end ? __int_as_float(m2.y) : 0.f;
            float n3 = j3 < end ? __int_as_float(m3.y) : 0.f;
            float4 v0 = *(const float4*)&H[(size_t)m0.x * C + c];
            float4 v1 = *(const float4*)&H[(size_t)m1.x * C + c];
            float4 v2 = *(const float4*)&H[(size_t)m2.x * C + c];
            float4 v3 = *(const float4*)&H[(size_t)m3.x * C + c];
            a0.x = fmaf(v0.x, n0, a0.x); a0.y = fmaf(v0.y, n0, a0.y);
            a0.z = fmaf(v0.z, n0, a0.z); a0.w = fmaf(v0.w, n0, a0.w);
            a1.x = fmaf(v1.x, n1, a1.x); a1.y = fmaf(v1.y, n1, a1.y);
            a1.z = fmaf(v1.z, n1, a1.z); a1.w = fmaf(v1.w, n1, a1.w);
            a2.x = fmaf(v2.x, n2, a2.x); a2.y = fmaf(v2.y, n2, a2.y);
            a2.z = fmaf(v2.z, n2, a2.z); a2.w = fmaf(v2.w, n2, a2.w);
            a3.x = fmaf(v3.x, n3, a3.x); a3.y = fmaf(v3.y, n3, a3.y);
            a3.z = fmaf(v3.z, n3, a3.z); a3.w = fmaf(v3.w, n3, a3.w);
        }
    }
    float4 acc = make_float4(a0.x + a1.x + a2.x + a3.x,
                             a0.y + a1.y + a2.y + a3.y,
                             a0.z + a1.z + a2.z + a3.z,
                             a0.w + a1.w + a2.w + a3.w);

    if (!POOL) {
        if (active) *(float4*)&outbuf[(size_t)d * C + c] = acc;
    } else {
        __shared__ float4 red[8][32];
        float4 v = make_float4(0.f, 0.f, 0.f, 0.f);
        if (active) {
            v.x = silu_f(acc.x + bias[c + 0]);
            v.y = silu_f(acc.y + bias[c + 1]);
            v.z = silu_f(acc.z + bias[c + 2]);
            v.w = silu_f(acc.w + bias[c + 3]);
        }
        red[g][l] = v;
        __syncthreads();
        if (threadIdx.x < 32) {
            float4 t = red[0][threadIdx.x];
            #pragma unroll
            for (int q = 1; q < 8; ++q) {
                float4 u = red[q][threadIdx.x];
                t.x += u.x; t.y += u.y; t.z += u.z; t.w += u.w;
            }
            *(float4*)&outbuf[(size_t)blockIdx.x * C + threadIdx.x * 4] = t;
        }
    }
}

// ---------- 2-stage reduce of partials -> out ----------

__global__ void reduce1_k(const float* __restrict__ partial, float* __restrict__ p2,
                          int NB, int chunk) {
    int t = threadIdx.x;                      // 128 = channel
    int r0 = blockIdx.x * chunk;
    int r1 = r0 + chunk; if (r1 > NB) r1 = NB;
    float s = 0.f;
    for (int r = r0; r < r1; ++r) s += partial[(size_t)r * C + t];
    p2[(size_t)blockIdx.x * C + t] = s;
}

__global__ void reduce2_k(const float* __restrict__ p2, float* __restrict__ out,
                          int R1, float inv_n) {
    int t = threadIdx.x;                      // 128 = channel
    float s = 0.f;
    for (int r = 0; r < R1; ++r) s += p2[(size_t)r * C + t];
    out[t] = s * inv_n;
}

// ---------- launch ----------

extern "C" void kernel_launch(void* const* d_in, const int* in_sizes, int n_in,
                              void* d_out, int out_size, void* d_ws, size_t ws_size,
                              hipStream_t stream) {
    const float* x  = (const float*)d_in[0];
    const int*   ei = (const int*)d_in[1];
    const float* ew = (const float*)d_in[2];
    const float* W1 = (const float*)d_in[3];
    const float* b1 = (const float*)d_in[4];
    const float* W2 = (const float*)d_in[5];
    const float* b2 = (const float*)d_in[6];
    const float* W3 = (const float*)d_in[7];
    const float* b3 = (const float*)d_in[8];
    float* out = (float*)d_out;

    const int N = in_sizes[0] / INCH;
    const int E = in_sizes[1] / 2;
    const int* src = ei;
    const int* dst = ei + E;

    char* ws = (char*)d_ws;
    size_t off = 0;
    auto alloc = [&](size_t bytes) -> void* {
        void* p = ws + off;
        off += (bytes + 255) & ~(size_t)255;
        return p;
    };
    float*  H      = (float*) alloc((size_t)N * C * sizeof(float));
    float*  AGG    = (float*) alloc((size_t)N * C * sizeof(float));
    int2*   edata  = (int2*)  alloc((size_t)E * sizeof(int2));
    int*    rowptr = (int*)   alloc((size_t)(N + 1) * sizeof(int));
    unsigned long long* packed = (unsigned long long*)alloc((size_t)N * 8);
    int*    counts = (int*)   alloc((size_t)N * sizeof(int));
    int*    cursor = (int*)   alloc((size_t)N * sizeof(int));
    float*  dinv   = (float*) alloc((size_t)N * sizeof(float));
    int*    bsums  = (int*)   alloc(256 * sizeof(int));
    (void)ws_size;

    const int nb = (N + 255) / 256;
    const int eb = (E + 255) / 256;
    const int sbk = (N + SCAN_E - 1) / SCAN_E;   // scan blocks (<=128)

    // normalization + CSR build
    init_k<<<nb, 256, 0, stream>>>(packed, cursor, N);
    hist_k<<<eb, 256, 0, stream>>>(dst, ew, packed, E);
    extract_k<<<nb, 256, 0, stream>>>(packed, counts, dinv, N);
    scan1_k<<<sbk, SCAN_T, 0, stream>>>(counts, rowptr, bsums, N);
    scan2_k<<<1, 128, 0, stream>>>(bsums, sbk);
    scan3_k<<<nb, 256, 0, stream>>>(rowptr, bsums, N, E);
    fill_csr_k<<<eb, 256, 0, stream>>>(src, dst, ew, dinv, rowptr, cursor, edata, E);

    const int gb = (N + 31) / 32;              // gemm blocks
    const int ab = (N + 7) / 8;                // agg blocks (8 nodes/block)

    // layer 1: x(64) -> H, aggregate -> AGG
    gemm_k<INCH, false><<<gb, 256, 0, stream>>>(x, W1, nullptr, H, N);
    agg_gather_k<false><<<ab, 256, 0, stream>>>(H, edata, rowptr, dinv, nullptr, AGG, N);
    // layer 2: silu(AGG+b1)(128) -> H, aggregate
    gemm_k<C, true><<<gb, 256, 0, stream>>>(AGG, W2, b1, H, N);
    agg_gather_k<false><<<ab, 256, 0, stream>>>(H, edata, rowptr, dinv, nullptr, AGG, N);
    // layer 3: gemm -> H, fused aggregate + bias + silu + block-pool -> partials (alias AGG)
    gemm_k<C, true><<<gb, 256, 0, stream>>>(AGG, W3, b2, H, N);
    float* partial = AGG;                      // AGG free in POOL mode
    agg_gather_k<true><<<ab, 256, 0, stream>>>(H, edata, rowptr, dinv, b3, partial, N);

    // 2-stage mean reduce: partial[ab][128] -> p2[R1][128] -> out[128]
    const int R1 = 100;
    const int chunk = (ab + R1 - 1) / R1;
    float* p2 = (float*)counts;                // counts free after scan
    reduce1_k<<<R1, 128, 0, stream>>>(partial, p2, ab, chunk);
    reduce2_k<<<1, 128, 0, stream>>>(p2, out, R1, 1.0f / (float)N);
}

// Round 9
// 668.212 us; speedup vs baseline: 1.2935x; 1.1052x over previous
//
#include <hip/hip_runtime.h>

#define C 128            // hidden/out channels
#define INCH 64          // input channels
#define FIXP 33554432.0f // 2^25 fixed-point scale for weighted degree

__device__ __forceinline__ float silu_f(float v) {
    return v / (1.0f + __expf(-v));
}

// ---------- small vector helpers (no cross-lane anywhere) ----------

template<int CH> struct VecSel;
template<> struct VecSel<128> { using T = float4; };
template<> struct VecSel<64>  { using T = float2; };

__device__ __forceinline__ float4 vfma(const float4 v, float n, float4 a) {
    a.x = fmaf(v.x, n, a.x); a.y = fmaf(v.y, n, a.y);
    a.z = fmaf(v.z, n, a.z); a.w = fmaf(v.w, n, a.w); return a;
}
__device__ __forceinline__ float2 vfma(const float2 v, float n, float2 a) {
    a.x = fmaf(v.x, n, a.x); a.y = fmaf(v.y, n, a.y); return a;
}
__device__ __forceinline__ float4 vmul(const float4 v, float s) {
    return make_float4(v.x * s, v.y * s, v.z * s, v.w * s);
}
__device__ __forceinline__ float2 vmul(const float2 v, float s) {
    return make_float2(v.x * s, v.y * s);
}
__device__ __forceinline__ float4 vadd(const float4 a, const float4 b) {
    return make_float4(a.x + b.x, a.y + b.y, a.z + b.z, a.w + b.w);
}
__device__ __forceinline__ float2 vadd(const float2 a, const float2 b) {
    return make_float2(a.x + b.x, a.y + b.y);
}

// ---------- preprocessing ----------

__global__ void init_k(unsigned long long* packed, int* cursor, int n) {
    int i = blockIdx.x * blockDim.x + threadIdx.x;
    if (i < n) { packed[i] = 0ull; cursor[i] = 0; }
}

// one u64 atomic per edge: hi32 = count, lo32 = fixed-point sum of w
__global__ void hist_k(const int* __restrict__ dst, const float* __restrict__ w,
                       unsigned long long* packed, int E) {
    int e = blockIdx.x * blockDim.x + threadIdx.x;
    if (e < E) {
        unsigned fx = (unsigned)(w[e] * FIXP + 0.5f);
        atomicAdd(&packed[dst[e]], (1ull << 32) | (unsigned long long)fx);
    }
}

__global__ void extract_k(const unsigned long long* __restrict__ packed,
                          int* counts, float* dinv, int n) {
    int i = blockIdx.x * blockDim.x + threadIdx.x;
    if (i < n) {
        unsigned long long p = packed[i];
        counts[i] = (int)(p >> 32);
        float deg = 1.0f + (float)(unsigned)(p & 0xffffffffull) * (1.0f / FIXP);
        dinv[i] = rsqrtf(deg);   // deg >= 1 (self-loop) so always > 0
    }
}

// ---------- exclusive scan of counts -> rowptr (1024 elems / block) ----------

#define SCAN_T 256
#define SCAN_E 1024

__global__ void scan1_k(const int* __restrict__ counts, int* rowptr, int* bsums, int N) {
    __shared__ int s[SCAN_T];
    int t = threadIdx.x;
    int base = blockIdx.x * SCAN_E + t * 4;
    int v[4];
    #pragma unroll
    for (int j = 0; j < 4; ++j) { int i = base + j; v[j] = (i < N) ? counts[i] : 0; }
    int sum = v[0] + v[1] + v[2] + v[3];
    s[t] = sum; __syncthreads();
    for (int off = 1; off < SCAN_T; off <<= 1) {
        int y = (t >= off) ? s[t - off] : 0;
        __syncthreads();
        s[t] += y;
        __syncthreads();
    }
    int incl = s[t];
    int excl = incl - sum;
    if (t == SCAN_T - 1) bsums[blockIdx.x] = incl;
    int run = excl;
    #pragma unroll
    for (int j = 0; j < 4; ++j) { int i = base + j; if (i < N) rowptr[i] = run; run += v[j]; }
}

__global__ void scan2_k(int* bsums, int nb) {
    __shared__ int s[128];
    int t = threadIdx.x;
    int v = (t < nb) ? bsums[t] : 0;
    s[t] = v; __syncthreads();
    for (int off = 1; off < 128; off <<= 1) {
        int y = (t >= off) ? s[t - off] : 0;
        __syncthreads();
        s[t] += y;
        __syncthreads();
    }
    if (t < nb) bsums[t] = s[t] - v;   // exclusive block offsets
}

__global__ void scan3_k(int* rowptr, const int* __restrict__ bsums, int N, int E) {
    int i = blockIdx.x * blockDim.x + threadIdx.x;
    if (i < N) rowptr[i] += bsums[i >> 10];
    if (i == 0) rowptr[N] = E;
}

// ---------- CSR fill: edata[pos] = {src, norm} (single 8B store) ----------

__global__ void fill_csr_k(const int* __restrict__ src, const int* __restrict__ dst,
                           const float* __restrict__ w, const float* __restrict__ dinv,
                           const int* __restrict__ rowptr, int* cursor,
                           int2* edata, int E) {
    int e = blockIdx.x * blockDim.x + threadIdx.x;
    if (e >= E) return;
    int s = src[e], d = dst[e];
    float nm = dinv[s] * w[e] * dinv[d];
    int pos = rowptr[d] + atomicAdd(&cursor[d], 1);
    edata[pos] = make_int2(s, __float_as_int(nm));
}

// ---------- aggregation (gather, raw): acc[d] = X[d]*dinv[d]^2 + sum_e X[src_e]*norm_e ----------
// Commuted GCN: aggregation runs BEFORE the GEMM (exact linear reassociation).
// one 32-lane group per dst node (8 nodes/block); lane owns CH/32 channels.
// Edge metadata read directly per group (same addr for 32 lanes -> broadcast load).
// NO cross-lane ops, no barriers. 4-deep unrolled, clamp-and-zero predication.

template<int CH>
__launch_bounds__(256)
__global__ void agg_gather_k(const float* __restrict__ H, const int2* __restrict__ edata,
                             const int* __restrict__ rowptr, const float* __restrict__ dinv,
                             float* __restrict__ outbuf, int N) {
    using VecT = typename VecSel<CH>::T;
    const int g = threadIdx.x >> 5;      // group 0..7
    const int l = threadIdx.x & 31;      // lane in group
    const int d = blockIdx.x * 8 + g;
    if (d >= N) return;                  // safe: no barriers, no cross-lane below
    const int c = l * (CH / 32);         // channel base

    float di = dinv[d];
    float d2 = di * di;
    VecT a0 = vmul(*(const VecT*)&H[(size_t)d * CH + c], d2);
    VecT a1 = {}, a2 = {}, a3 = {};
    const int beg = rowptr[d], end = rowptr[d + 1];
    for (int j = beg; j < end; j += 4) {
        int j1 = j + 1, j2 = j + 2, j3 = j + 3;
        int2 m0 = edata[j];
        int2 m1 = edata[j1 < end ? j1 : j];
        int2 m2 = edata[j2 < end ? j2 : j];
        int2 m3 = edata[j3 < end ? j3 : j];
        float n0 = __int_as_float(m0.y);
        float n1 = j1 < end ? __int_as_float(m1.y) : 0.f;
        float n2 = j2 < end ? __int_as_float(m2.y) : 0.f;
        float n3 = j3 < end ? __int_as_float(m3.y) : 0.f;
        VecT v0 = *(const VecT*)&H[(size_t)m0.x * CH + c];
        VecT v1 = *(const VecT*)&H[(size_t)m1.x * CH + c];
        VecT v2 = *(const VecT*)&H[(size_t)m2.x * CH + c];
        VecT v3 = *(const VecT*)&H[(size_t)m3.x * CH + c];
        a0 = vfma(v0, n0, a0);
        a1 = vfma(v1, n1, a1);
        a2 = vfma(v2, n2, a2);
        a3 = vfma(v3, n3, a3);
    }
    VecT acc = vadd(vadd(a0, a1), vadd(a2, a3));
    *(VecT*)&outbuf[(size_t)d * CH + c] = acc;
}

// ---------- GEMM: out = silu(x @ W + bias) ----------
// POOL=false: write per-row. POOL=true: column-sum into partial[block][128].
// 256 threads/block, 32 rows x 128 cols, 4x4 register tile (validated round-6 loop).

template<int K, bool POOL>
__launch_bounds__(256, 2)
__global__ void gemm_k(const float* __restrict__ x, const float* __restrict__ W,
                       const float* __restrict__ bias, float* __restrict__ out, int N) {
    __shared__ float Ws[K][C];
    __shared__ float Xs[32][K];
    const int tid = threadIdx.x;
    const int r0 = blockIdx.x * 32;

    for (int i4 = tid; i4 < (K * C) / 4; i4 += 256) {
        *(float4*)&Ws[(i4 * 4) / C][(i4 * 4) % C] = *(const float4*)&W[i4 * 4];
    }
    for (int i4 = tid; i4 < (32 * K) / 4; i4 += 256) {
        int base = i4 * 4;
        int r = base / K, k = base % K;
        float4 v = make_float4(0.f, 0.f, 0.f, 0.f);
        if (r0 + r < N) v = *(const float4*)&x[(size_t)(r0 + r) * K + k];
        *(float4*)&Xs[r][k] = v;
    }
    __syncthreads();

    const int cg = (tid & 31) * 4;   // col base (0..124)
    const int rg = (tid >> 5) * 4;   // row base (0..28)
    float acc[4][4] = {};
    for (int k = 0; k < K; ++k) {
        float4 wv = *(const float4*)&Ws[k][cg];
        float xr0 = Xs[rg + 0][k];
        float xr1 = Xs[rg + 1][k];
        float xr2 = Xs[rg + 2][k];
        float xr3 = Xs[rg + 3][k];
        acc[0][0] = fmaf(xr0, wv.x, acc[0][0]); acc[0][1] = fmaf(xr0, wv.y, acc[0][1]);
        acc[0][2] = fmaf(xr0, wv.z, acc[0][2]); acc[0][3] = fmaf(xr0, wv.w, acc[0][3]);
        acc[1][0] = fmaf(xr1, wv.x, acc[1][0]); acc[1][1] = fmaf(xr1, wv.y, acc[1][1]);
        acc[1][2] = fmaf(xr1, wv.z, acc[1][2]); acc[1][3] = fmaf(xr1, wv.w, acc[1][3]);
        acc[2][0] = fmaf(xr2, wv.x, acc[2][0]); acc[2][1] = fmaf(xr2, wv.y, acc[2][1]);
        acc[2][2] = fmaf(xr2, wv.z, acc[2][2]); acc[2][3] = fmaf(xr2, wv.w, acc[2][3]);
        acc[3][0] = fmaf(xr3, wv.x, acc[3][0]); acc[3][1] = fmaf(xr3, wv.y, acc[3][1]);
        acc[3][2] = fmaf(xr3, wv.z, acc[3][2]); acc[3][3] = fmaf(xr3, wv.w, acc[3][3]);
    }

    float4 bv = *(const float4*)&bias[cg];
    if (!POOL) {
        #pragma unroll
        for (int i = 0; i < 4; ++i) {
            int r = r0 + rg + i;
            if (r < N) {
                float4 o;
                o.x = silu_f(acc[i][0] + bv.x);
                o.y = silu_f(acc[i][1] + bv.y);
                o.z = silu_f(acc[i][2] + bv.z);
                o.w = silu_f(acc[i][3] + bv.w);
                *(float4*)&out[(size_t)r * C + cg] = o;
            }
        }
    } else {
        float4 s = make_float4(0.f, 0.f, 0.f, 0.f);
        #pragma unroll
        for (int i = 0; i < 4; ++i) {
            int r = r0 + rg + i;
            if (r < N) {
                s.x += silu_f(acc[i][0] + bv.x);
                s.y += silu_f(acc[i][1] + bv.y);
                s.z += silu_f(acc[i][2] + bv.z);
                s.w += silu_f(acc[i][3] + bv.w);
            }
        }
        __syncthreads();                         // done reading Xs; reuse as reduce buf
        float4* red = (float4*)&Xs[0][0];        // [8][32] float4 = 4 KB <= Xs
        red[(tid >> 5) * 32 + (tid & 31)] = s;
        __syncthreads();
        if (tid < 32) {
            float4 t = red[tid];
            #pragma unroll
            for (int q = 1; q < 8; ++q) {
                float4 u = red[q * 32 + tid];
                t.x += u.x; t.y += u.y; t.z += u.z; t.w += u.w;
            }
            *(float4*)&out[(size_t)blockIdx.x * C + tid * 4] = t;
        }
    }
}

// ---------- 2-stage reduce of partials -> out ----------

__global__ void reduce1_k(const float* __restrict__ partial, float* __restrict__ p2,
                          int NB, int chunk) {
    int t = threadIdx.x;                      // 128 = channel
    int r0 = blockIdx.x * chunk;
    int r1 = r0 + chunk; if (r1 > NB) r1 = NB;
    float s = 0.f;
    for (int r = r0; r < r1; ++r) s += partial[(size_t)r * C + t];
    p2[(size_t)blockIdx.x * C + t] = s;
}

__global__ void reduce2_k(const float* __restrict__ p2, float* __restrict__ out,
                          int R1, float inv_n) {
    int t = threadIdx.x;                      // 128 = channel
    float s = 0.f;
    for (int r = 0; r < R1; ++r) s += p2[(size_t)r * C + t];
    out[t] = s * inv_n;
}

// ---------- launch ----------

extern "C" void kernel_launch(void* const* d_in, const int* in_sizes, int n_in,
                              void* d_out, int out_size, void* d_ws, size_t ws_size,
                              hipStream_t stream) {
    const float* x  = (const float*)d_in[0];
    const int*   ei = (const int*)d_in[1];
    const float* ew = (const float*)d_in[2];
    const float* W1 = (const float*)d_in[3];
    const float* b1 = (const float*)d_in[4];
    const float* W2 = (const float*)d_in[5];
    const float* b2 = (const float*)d_in[6];
    const float* W3 = (const float*)d_in[7];
    const float* b3 = (const float*)d_in[8];
    float* out = (float*)d_out;

    const int N = in_sizes[0] / INCH;
    const int E = in_sizes[1] / 2;
    const int* src = ei;
    const int* dst = ei + E;

    char* ws = (char*)d_ws;
    size_t off = 0;
    auto alloc = [&](size_t bytes) -> void* {
        void* p = ws + off;
        off += (bytes + 255) & ~(size_t)255;
        return p;
    };
    float*  A      = (float*) alloc((size_t)N * C * sizeof(float));  // agg outputs
    float*  X      = (float*) alloc((size_t)N * C * sizeof(float));  // activations
    int2*   edata  = (int2*)  alloc((size_t)E * sizeof(int2));
    int*    rowptr = (int*)   alloc((size_t)(N + 1) * sizeof(int));
    unsigned long long* packed = (unsigned long long*)alloc((size_t)N * 8);
    int*    counts = (int*)   alloc((size_t)N * sizeof(int));
    int*    cursor = (int*)   alloc((size_t)N * sizeof(int));
    float*  dinv   = (float*) alloc((size_t)N * sizeof(float));
    int*    bsums  = (int*)   alloc(256 * sizeof(int));
    (void)ws_size;

    const int nb = (N + 255) / 256;
    const int eb = (E + 255) / 256;
    const int sbk = (N + SCAN_E - 1) / SCAN_E;   // scan blocks (<=128)

    // normalization + CSR build
    init_k<<<nb, 256, 0, stream>>>(packed, cursor, N);
    hist_k<<<eb, 256, 0, stream>>>(dst, ew, packed, E);
    extract_k<<<nb, 256, 0, stream>>>(packed, counts, dinv, N);
    scan1_k<<<sbk, SCAN_T, 0, stream>>>(counts, rowptr, bsums, N);
    scan2_k<<<1, 128, 0, stream>>>(bsums, sbk);
    scan3_k<<<nb, 256, 0, stream>>>(rowptr, bsums, N, E);
    fill_csr_k<<<eb, 256, 0, stream>>>(src, dst, ew, dinv, rowptr, cursor, edata, E);

    const int gb = (N + 31) / 32;              // gemm blocks
    const int ab = (N + 7) / 8;                // agg blocks (8 nodes/block)

    // commuted layers: y = silu(agg(x) @ W + b)   [exact reassociation of reference]
    // layer 1: A = agg(x) on 64 ch; X = silu(A@W1 + b1)
    agg_gather_k<INCH><<<ab, 256, 0, stream>>>(x, edata, rowptr, dinv, A, N);
    gemm_k<INCH, false><<<gb, 256, 0, stream>>>(A, W1, b1, X, N);
    // layer 2: A = agg(X); X = silu(A@W2 + b2)
    agg_gather_k<C><<<ab, 256, 0, stream>>>(X, edata, rowptr, dinv, A, N);
    gemm_k<C, false><<<gb, 256, 0, stream>>>(A, W2, b2, X, N);
    // layer 3: A = agg(X); partial[block] = colsum(silu(A@W3 + b3))
    agg_gather_k<C><<<ab, 256, 0, stream>>>(X, edata, rowptr, dinv, A, N);
    float* partial = X;                        // X free after agg consumed it
    gemm_k<C, true><<<gb, 256, 0, stream>>>(A, W3, b3, partial, N);

    // 2-stage mean reduce: partial[gb][128] -> p2[R1][128] -> out[128]
    const int R1 = 64;
    const int chunk = (gb + R1 - 1) / R1;
    float* p2 = (float*)counts;                // counts free after scan
    reduce1_k<<<R1, 128, 0, stream>>>(partial, p2, gb, chunk);
    reduce2_k<<<1, 128, 0, stream>>>(p2, out, R1, 1.0f / (float)N);
}